// Round 2
// baseline (359.540 us; speedup 1.0000x reference)
//
#include <hip/hip_runtime.h>
#include <hip/hip_bf16.h>

#define BB 16
#define NI 2048
#define NA 2048
#define DD 256
#define KVB 32
#define NT (NA / KVB)   // 64

typedef __attribute__((ext_vector_type(8))) short short8;   // 8 bf16 = 4 VGPR
typedef __attribute__((ext_vector_type(4))) float f32x4;

static __device__ __forceinline__ unsigned short f2bf(float f) {
  union { float f; unsigned int u; } x; x.f = f;
  unsigned int r = x.u + 0x7fffu + ((x.u >> 16) & 1u);   // RNE
  return (unsigned short)(r >> 16);
}
static __device__ __forceinline__ float bf2f(unsigned short h) {
  union { unsigned int u; float f; } x; x.u = ((unsigned int)h) << 16;
  return x.f;
}

// ---------------- fused prep: attendee -> ahi_sw/alo_sw (row-XOR-swizzled) + vt (transposed hi) ----
// swizzle: within each 256-elem row, 16B unit u stored at u ^ (j&7)  (XOR-closed within 64-d slices)
__global__ void prep_kernel(const float* __restrict__ a,
                            unsigned short* __restrict__ ahisw,
                            unsigned short* __restrict__ alosw,
                            unsigned short* __restrict__ vt) {
  __shared__ float t[64][65];
  int bx = blockIdx.x;
  int b = bx >> 7;            // 128 tiles per batch
  int r = bx & 127;
  int jt = r >> 2, dt = r & 3;
  int j0 = jt * 64, d0 = dt * 64;
  int tid = threadIdx.x;
  int rr = tid >> 4, c4 = tid & 15;
#pragma unroll
  for (int k = 0; k < 4; ++k) {
    int row = rr + k * 16;
    int j = j0 + row;
    float4 v = *(const float4*)(a + ((size_t)b * NA + j) * DD + d0 + c4 * 4);
    ushort4 h, l;
    h.x = f2bf(v.x); l.x = f2bf(v.x - bf2f(h.x));
    h.y = f2bf(v.y); l.y = f2bf(v.y - bf2f(h.y));
    h.z = f2bf(v.z); l.z = f2bf(v.z - bf2f(h.z));
    h.w = f2bf(v.w); l.w = f2bf(v.w - bf2f(h.w));
    int u = (d0 >> 3) + (c4 >> 1);          // global 16B-unit index 0..31
    int us = u ^ (j & 7);
    size_t rb = ((size_t)b * NA + j) * DD + us * 8 + (c4 & 1) * 4;
    *(ushort4*)(ahisw + rb) = h;
    *(ushort4*)(alosw + rb) = l;
    t[row][c4 * 4 + 0] = v.x; t[row][c4 * 4 + 1] = v.y;
    t[row][c4 * 4 + 2] = v.z; t[row][c4 * 4 + 3] = v.w;
  }
  __syncthreads();
#pragma unroll
  for (int k = 0; k < 4; ++k) {
    int d = rr + k * 16;
    ushort4 o;
    o.x = f2bf(t[c4 * 4 + 0][d]); o.y = f2bf(t[c4 * 4 + 1][d]);
    o.z = f2bf(t[c4 * 4 + 2][d]); o.w = f2bf(t[c4 * 4 + 3][d]);
    *(ushort4*)(vt + ((size_t)b * DD + d0 + d) * NA + j0 + c4 * 4) = o;
  }
}

// ---------------- transpose + split W -> wt[e][d] hi/lo ----------------
__global__ void tw_kernel(const float* __restrict__ w,
                          unsigned short* __restrict__ wthi,
                          unsigned short* __restrict__ wtlo) {
  __shared__ float t[64][65];
  int bx = blockIdx.x;
  int dt = bx >> 2, et = bx & 3;
  int d0 = dt * 64, e0 = et * 64;
  int tid = threadIdx.x;
  int rr = tid >> 4, c4 = (tid & 15) * 4;
#pragma unroll
  for (int k = 0; k < 4; ++k) {
    int row = rr + k * 16;   // d index
    float4 v = *(const float4*)(w + (size_t)(d0 + row) * DD + e0 + c4);
    t[row][c4 + 0] = v.x; t[row][c4 + 1] = v.y; t[row][c4 + 2] = v.z; t[row][c4 + 3] = v.w;
  }
  __syncthreads();
#pragma unroll
  for (int k = 0; k < 4; ++k) {
    int e = rr + k * 16;
    ushort4 h, l;
    float v0 = t[c4 + 0][e]; h.x = f2bf(v0); l.x = f2bf(v0 - bf2f(h.x));
    float v1 = t[c4 + 1][e]; h.y = f2bf(v1); l.y = f2bf(v1 - bf2f(h.y));
    float v2 = t[c4 + 2][e]; h.z = f2bf(v2); l.z = f2bf(v2 - bf2f(h.z));
    float v3 = t[c4 + 3][e]; h.w = f2bf(v3); l.w = f2bf(v3 - bf2f(h.w));
    *(ushort4*)(wthi + (size_t)(e0 + e) * DD + d0 + c4) = h;
    *(ushort4*)(wtlo + (size_t)(e0 + e) * DD + d0 + c4) = l;
  }
}

// ---------------- Q = x @ W  (split-bf16 MFMA), writes qhi/qlo (plain row-major) ----------------
__global__ __launch_bounds__(256, 2) void qgemm_kernel(
    const float* __restrict__ x, const unsigned short* __restrict__ wthi,
    const unsigned short* __restrict__ wtlo,
    unsigned short* __restrict__ qhi, unsigned short* __restrict__ qlo) {
  __shared__ unsigned short xb[64 * 256];   // 32 KB, XOR-swizzled
  const int tid = threadIdx.x;
  const int lane = tid & 63;
  const int wv = tid >> 6;       // 0..3
  const int quad = lane >> 4;
  const int l16 = lane & 15;
  const int m0 = blockIdx.x * 64;

  short8 xhf[8], xlf[8];
#pragma unroll
  for (int s = 0; s < 2; ++s) {
    for (int c = tid; c < 64 * 64; c += 256) {   // 64 rows x 64 float4
      int row = c >> 6, c4 = c & 63;
      float4 v = *(const float4*)(x + (size_t)(m0 + row) * DD + c4 * 4);
      ushort4 o;
      if (s == 0) {
        o.x = f2bf(v.x); o.y = f2bf(v.y); o.z = f2bf(v.z); o.w = f2bf(v.w);
      } else {
        unsigned short h;
        h = f2bf(v.x); o.x = f2bf(v.x - bf2f(h));
        h = f2bf(v.y); o.y = f2bf(v.y - bf2f(h));
        h = f2bf(v.z); o.z = f2bf(v.z - bf2f(h));
        h = f2bf(v.w); o.w = f2bf(v.w - bf2f(h));
      }
      *(ushort4*)(xb + row * 256 + (((c4 >> 1) ^ (row & 7)) * 8) + (c4 & 1) * 4) = o;
    }
    __syncthreads();
    {
      int r = wv * 16 + l16;
#pragma unroll
      for (int c = 0; c < 8; ++c) {
        short8 v = *(const short8*)(xb + r * 256 + (((4 * c + quad) ^ (r & 7)) * 8));
        if (s == 0) xhf[c] = v; else xlf[c] = v;
      }
    }
    __syncthreads();
  }

#pragma unroll 1
  for (int et = 0; et < 16; ++et) {
    int e0 = et * 16;
    f32x4 acc; acc[0] = acc[1] = acc[2] = acc[3] = 0.f;
#pragma unroll
    for (int c = 0; c < 8; ++c) {
      short8 wh = *(const short8*)((const short*)wthi + (size_t)(e0 + l16) * DD + c * 32 + quad * 8);
      short8 wl = *(const short8*)((const short*)wtlo + (size_t)(e0 + l16) * DD + c * 32 + quad * 8);
      acc = __builtin_amdgcn_mfma_f32_16x16x32_bf16(xhf[c], wh, acc, 0, 0, 0);
      acc = __builtin_amdgcn_mfma_f32_16x16x32_bf16(xlf[c], wh, acc, 0, 0, 0);
      acc = __builtin_amdgcn_mfma_f32_16x16x32_bf16(xhf[c], wl, acc, 0, 0, 0);
    }
#pragma unroll
    for (int rg = 0; rg < 4; ++rg) {
      float q = acc[rg];
      unsigned short h = f2bf(q);
      unsigned short l = f2bf(q - bf2f(h));
      size_t off = (size_t)(m0 + wv * 16 + 4 * quad + rg) * DD + e0 + l16;
      qhi[off] = h; qlo[off] = l;
    }
  }
}

// ---------------- flash attention v2 ----------------
// 8 waves = 4 q-groups x 2 roles. QBLK=128 (32 q per wave, K-frags reused over 2 q-tiles).
// Pair splits j (QK^T) and d (PV); P shared via LDS. K hi/lo staged in LDS (pre-swizzled,
// reg-prefetched T14); V and Q fragments read directly from L2. Defer-max online softmax.
__global__ __launch_bounds__(512, 2) void attn_kernel(
    const unsigned short* __restrict__ ahisw, const unsigned short* __restrict__ alosw,
    const unsigned short* __restrict__ vt,
    const unsigned short* __restrict__ qhi, const unsigned short* __restrict__ qlo,
    float* __restrict__ out) {
  __shared__ unsigned short khi[KVB * DD];      // 16 KB
  __shared__ unsigned short kli[KVB * DD];      // 16 KB
  __shared__ unsigned short pls[4 * 32 * 32];   // 8 KB   P[group][q(32)][j(32)]
  __shared__ float scm[4][2][32];               // pmax partials
  __shared__ float scs[4][2][32];               // psum partials

  const int tid = threadIdx.x;
  const int lane = tid & 63;
  const int wv = tid >> 6;       // 0..7
  const int g = wv >> 1;         // q-group 0..3
  const int h = wv & 1;          // j-half (QK^T) / d-half (PV)
  const int quad = lane >> 4;
  const int l16 = lane & 15;

  int bx = blockIdx.x;
  int lbx = (bx & 7) * 32 + (bx >> 3);   // XCD-chunked swizzle: 2 batches per XCD
  const int b = lbx >> 4;
  const int qt16 = lbx & 15;
  const int qbase = qt16 * 128 + g * 32;

  const size_t abase = (size_t)b * NA * DD;
  const size_t vbase = (size_t)b * (size_t)DD * NA;

  // ---- Q fragments straight from global (one-time, L2) ----
  short8 qh[2][8], ql[2][8];
#pragma unroll
  for (int qt = 0; qt < 2; ++qt) {
    const size_t qrow = ((size_t)b * NI + qbase + qt * 16 + l16) * DD;
#pragma unroll
    for (int c = 0; c < 8; ++c) {
      qh[qt][c] = *(const short8*)(qhi + qrow + c * 32 + quad * 8);
      ql[qt][c] = *(const short8*)(qlo + qrow + c * 32 + quad * 8);
    }
  }

  f32x4 acc[2][8];
#pragma unroll
  for (int qt = 0; qt < 2; ++qt)
#pragma unroll
    for (int dt = 0; dt < 8; ++dt) { acc[qt][dt][0] = 0.f; acc[qt][dt][1] = 0.f; acc[qt][dt][2] = 0.f; acc[qt][dt][3] = 0.f; }
  float m_used0 = -INFINITY, m_used1 = -INFINITY;
  float l0 = 0.f, l1 = 0.f;

  // ---- stage kt=0 K tiles (linear copy; source is pre-swizzled) ----
  {
    const unsigned short* sh = ahisw + abase;
    const unsigned short* sl = alosw + abase;
    *(uint4*)(khi + tid * 8)        = *(const uint4*)(sh + tid * 8);
    *(uint4*)(khi + 4096 + tid * 8) = *(const uint4*)(sh + 4096 + tid * 8);
    *(uint4*)(kli + tid * 8)        = *(const uint4*)(sl + tid * 8);
    *(uint4*)(kli + 4096 + tid * 8) = *(const uint4*)(sl + 4096 + tid * 8);
  }
  __syncthreads();

#pragma unroll 1
  for (int kt = 0; kt < NT; ++kt) {
    const int jb = kt * KVB;

    // ---- T14 prefetch of next K tile into regs (issued a full phase early) ----
    uint4 pf0, pf1, pf2, pf3;
    if (kt + 1 < NT) {
      const unsigned short* sh = ahisw + abase + (size_t)(jb + KVB) * DD;
      const unsigned short* sl = alosw + abase + (size_t)(jb + KVB) * DD;
      pf0 = *(const uint4*)(sh + tid * 8);
      pf1 = *(const uint4*)(sh + 4096 + tid * 8);
      pf2 = *(const uint4*)(sl + tid * 8);
      pf3 = *(const uint4*)(sl + 4096 + tid * 8);
    }

    // ---- phase A: S^T (16 j x 32 q), split precision ----
    const int jr = h * 16 + l16;
    f32x4 st0, st1;
    st0[0] = st0[1] = st0[2] = st0[3] = 0.f;
    st1[0] = st1[1] = st1[2] = st1[3] = 0.f;
#pragma unroll
    for (int c = 0; c < 8; ++c) {
      int off = jr * DD + (((4 * c + quad) ^ (jr & 7)) * 8);
      short8 kh = *(const short8*)(khi + off);
      short8 kl = *(const short8*)(kli + off);
      st0 = __builtin_amdgcn_mfma_f32_16x16x32_bf16(kh, qh[0][c], st0, 0, 0, 0);
      st1 = __builtin_amdgcn_mfma_f32_16x16x32_bf16(kh, qh[1][c], st1, 0, 0, 0);
      st0 = __builtin_amdgcn_mfma_f32_16x16x32_bf16(kh, ql[0][c], st0, 0, 0, 0);
      st1 = __builtin_amdgcn_mfma_f32_16x16x32_bf16(kh, ql[1][c], st1, 0, 0, 0);
      st0 = __builtin_amdgcn_mfma_f32_16x16x32_bf16(kl, qh[0][c], st0, 0, 0, 0);
      st1 = __builtin_amdgcn_mfma_f32_16x16x32_bf16(kl, qh[1][c], st1, 0, 0, 0);
    }

    // ---- partial max over this wave's 16 j ----
    float p0 = fmaxf(fmaxf(st0[0], st0[1]), fmaxf(st0[2], st0[3]));
    float p1 = fmaxf(fmaxf(st1[0], st1[1]), fmaxf(st1[2], st1[3]));
    p0 = fmaxf(p0, __shfl_xor(p0, 16)); p0 = fmaxf(p0, __shfl_xor(p0, 32));
    p1 = fmaxf(p1, __shfl_xor(p1, 16)); p1 = fmaxf(p1, __shfl_xor(p1, 32));
    if (quad == 0) { scm[g][h][l16] = p0; scm[g][h][16 + l16] = p1; }
    __syncthreads();   // b1

    float pm0 = fmaxf(p0, scm[g][h ^ 1][l16]);
    float pm1 = fmaxf(p1, scm[g][h ^ 1][16 + l16]);
    bool upd = __any((pm0 > m_used0 + 8.f) || (pm1 > m_used1 + 8.f)) != 0;
    if (upd) {
      float mn0 = fmaxf(m_used0, pm0), mn1 = fmaxf(m_used1, pm1);
      float sc0 = __expf(m_used0 - mn0), sc1 = __expf(m_used1 - mn1);
      l0 *= sc0; l1 *= sc1;
      float a0 = __shfl(sc0, 4 * quad + 0), a1 = __shfl(sc0, 4 * quad + 1);
      float a2 = __shfl(sc0, 4 * quad + 2), a3 = __shfl(sc0, 4 * quad + 3);
      float b0 = __shfl(sc1, 4 * quad + 0), b1_ = __shfl(sc1, 4 * quad + 1);
      float b2 = __shfl(sc1, 4 * quad + 2), b3 = __shfl(sc1, 4 * quad + 3);
#pragma unroll
      for (int dt = 0; dt < 8; ++dt) {
        acc[0][dt][0] *= a0; acc[0][dt][1] *= a1; acc[0][dt][2] *= a2; acc[0][dt][3] *= a3;
        acc[1][dt][0] *= b0; acc[1][dt][1] *= b1_; acc[1][dt][2] *= b2; acc[1][dt][3] *= b3;
      }
      m_used0 = mn0; m_used1 = mn1;
    }

    // ---- stage next K tile (buffer free after b1; consumed after b2) ----
    if (kt + 1 < NT) {
      *(uint4*)(khi + tid * 8) = pf0; *(uint4*)(khi + 4096 + tid * 8) = pf1;
      *(uint4*)(kli + tid * 8) = pf2; *(uint4*)(kli + 4096 + tid * 8) = pf3;
    }

    // ---- P = exp(S - m_used); partial sums; write P to LDS ----
    float e00 = __expf(st0[0] - m_used0), e01 = __expf(st0[1] - m_used0);
    float e02 = __expf(st0[2] - m_used0), e03 = __expf(st0[3] - m_used0);
    float e10 = __expf(st1[0] - m_used1), e11 = __expf(st1[1] - m_used1);
    float e12 = __expf(st1[2] - m_used1), e13 = __expf(st1[3] - m_used1);
    float s0 = (e00 + e01) + (e02 + e03);
    float s1 = (e10 + e11) + (e12 + e13);
    s0 += __shfl_xor(s0, 16); s0 += __shfl_xor(s0, 32);
    s1 += __shfl_xor(s1, 16); s1 += __shfl_xor(s1, 32);
    {
      int uw = h * 2 + (quad >> 1);
      int sub = (quad & 1) * 4;
      ushort4 pk;
      pk.x = f2bf(e00); pk.y = f2bf(e01); pk.z = f2bf(e02); pk.w = f2bf(e03);
      int q0 = l16;
      *(ushort4*)(pls + g * 1024 + q0 * 32 + ((uw ^ (q0 & 3)) * 8) + sub) = pk;
      pk.x = f2bf(e10); pk.y = f2bf(e11); pk.z = f2bf(e12); pk.w = f2bf(e13);
      int q1 = 16 + l16;
      *(ushort4*)(pls + g * 1024 + q1 * 32 + ((uw ^ (q1 & 3)) * 8) + sub) = pk;
    }
    if (quad == 0) { scs[g][h][l16] = s0; scs[g][h][16 + l16] = s1; }
    __syncthreads();   // b2

    l0 += s0 + scs[g][h ^ 1][l16];
    l1 += s1 + scs[g][h ^ 1][16 + l16];

    // ---- phase B: PV (this wave's d-half), V frags direct from L2 ----
    short8 pa0 = *(const short8*)(pls + g * 1024 + l16 * 32 + ((quad ^ (l16 & 3)) * 8));
    short8 pa1 = *(const short8*)(pls + g * 1024 + (16 + l16) * 32 + ((quad ^ ((16 + l16) & 3)) * 8));
#pragma unroll
    for (int dt = 0; dt < 8; ++dt) {
      int d = h * 128 + dt * 16 + l16;
      short8 vb = *(const short8*)(vt + vbase + (size_t)d * NA + jb + quad * 8);
      acc[0][dt] = __builtin_amdgcn_mfma_f32_16x16x32_bf16(pa0, vb, acc[0][dt], 0, 0, 0);
      acc[1][dt] = __builtin_amdgcn_mfma_f32_16x16x32_bf16(pa1, vb, acc[1][dt], 0, 0, 0);
    }
  }

  // ---- epilogue: normalize + store ----
  float inv0 = 1.0f / l0, inv1 = 1.0f / l1;
  float i00 = __shfl(inv0, 4 * quad + 0), i01 = __shfl(inv0, 4 * quad + 1);
  float i02 = __shfl(inv0, 4 * quad + 2), i03 = __shfl(inv0, 4 * quad + 3);
  float i10 = __shfl(inv1, 4 * quad + 0), i11 = __shfl(inv1, 4 * quad + 1);
  float i12 = __shfl(inv1, 4 * quad + 2), i13 = __shfl(inv1, 4 * quad + 3);
  size_t ob = ((size_t)b * NI + qbase) * DD + h * 128;
#pragma unroll
  for (int dt = 0; dt < 8; ++dt) {
    int d = dt * 16 + l16;
    out[ob + (size_t)(4 * quad + 0) * DD + d] = acc[0][dt][0] * i00;
    out[ob + (size_t)(4 * quad + 1) * DD + d] = acc[0][dt][1] * i01;
    out[ob + (size_t)(4 * quad + 2) * DD + d] = acc[0][dt][2] * i02;
    out[ob + (size_t)(4 * quad + 3) * DD + d] = acc[0][dt][3] * i03;
    out[ob + (size_t)(16 + 4 * quad + 0) * DD + d] = acc[1][dt][0] * i10;
    out[ob + (size_t)(16 + 4 * quad + 1) * DD + d] = acc[1][dt][1] * i11;
    out[ob + (size_t)(16 + 4 * quad + 2) * DD + d] = acc[1][dt][2] * i12;
    out[ob + (size_t)(16 + 4 * quad + 3) * DD + d] = acc[1][dt][3] * i13;
  }
}

extern "C" void kernel_launch(void* const* d_in, const int* in_sizes, int n_in,
                              void* d_out, int out_size, void* d_ws, size_t ws_size,
                              hipStream_t stream) {
  const float* x = (const float*)d_in[0];        // [16,2048,256]
  const float* att = (const float*)d_in[1];      // [16,2048,256]
  const float* W = (const float*)d_in[2];        // [256,256]
  float* out = (float*)d_out;

  const size_t NE = (size_t)BB * NA * DD;        // 8388608
  unsigned short* w0    = (unsigned short*)d_ws;
  unsigned short* ahisw = w0;
  unsigned short* alosw = w0 + NE;
  unsigned short* vt    = w0 + 2 * NE;
  unsigned short* qhi   = w0 + 3 * NE;
  unsigned short* qlo   = w0 + 4 * NE;
  unsigned short* wthi  = w0 + 5 * NE;
  unsigned short* wtlo  = w0 + 5 * NE + (size_t)DD * DD;

  prep_kernel<<<2048, 256, 0, stream>>>(att, ahisw, alosw, vt);
  tw_kernel<<<16, 256, 0, stream>>>(W, wthi, wtlo);
  qgemm_kernel<<<512, 256, 0, stream>>>(x, wthi, wtlo, qhi, qlo);
  attn_kernel<<<256, 512, 0, stream>>>(ahisw, alosw, vt, qhi, qlo, out);
}

// Round 3
// 341.316 us; speedup vs baseline: 1.0534x; 1.0534x over previous
//
#include <hip/hip_runtime.h>
#include <hip/hip_bf16.h>

#define BB 16
#define NI 2048
#define NA 2048
#define DD 256
#define KVB 32
#define NT (NA / KVB)   // 64

typedef _Float16 half8 __attribute__((ext_vector_type(8)));
typedef __attribute__((ext_vector_type(4))) float f32x4;

static __device__ __forceinline__ unsigned short f2h(float f) {
  union { _Float16 h; unsigned short u; } x; x.h = (_Float16)f; return x.u;
}
static __device__ __forceinline__ float h2f(unsigned short u) {
  union { _Float16 h; unsigned short u; } x; x.u = u; return (float)x.h;
}

// ---------------- prep: attendee -> ksw (fp16, row-XOR-swizzled) + vt (fp16, transposed) ----
__global__ void prep_kernel(const float* __restrict__ a,
                            unsigned short* __restrict__ ksw,
                            unsigned short* __restrict__ vt) {
  __shared__ float t[64][65];
  int bx = blockIdx.x;
  int b = bx >> 7;
  int r = bx & 127;
  int jt = r >> 2, dt = r & 3;
  int j0 = jt * 64, d0 = dt * 64;
  int tid = threadIdx.x;
  int rr = tid >> 4, c4 = tid & 15;
#pragma unroll
  for (int k = 0; k < 4; ++k) {
    int row = rr + k * 16;
    int j = j0 + row;
    float4 v = *(const float4*)(a + ((size_t)b * NA + j) * DD + d0 + c4 * 4);
    ushort4 hh;
    hh.x = f2h(v.x); hh.y = f2h(v.y); hh.z = f2h(v.z); hh.w = f2h(v.w);
    int dd = d0 + c4 * 4;
    int u = dd >> 3, sub = dd & 7;            // sub in {0,4}
    int us = u ^ (j & 7);
    *(ushort4*)(ksw + ((size_t)b * NA + j) * DD + us * 8 + sub) = hh;
    t[row][c4 * 4 + 0] = v.x; t[row][c4 * 4 + 1] = v.y;
    t[row][c4 * 4 + 2] = v.z; t[row][c4 * 4 + 3] = v.w;
  }
  __syncthreads();
#pragma unroll
  for (int k = 0; k < 4; ++k) {
    int d = rr + k * 16;
    ushort4 o;
    o.x = f2h(t[c4 * 4 + 0][d]); o.y = f2h(t[c4 * 4 + 1][d]);
    o.z = f2h(t[c4 * 4 + 2][d]); o.w = f2h(t[c4 * 4 + 3][d]);
    *(ushort4*)(vt + ((size_t)b * DD + d0 + d) * NA + j0 + c4 * 4) = o;
  }
}

// ---------------- tw: W -> W^T hi/lo fp16, row-XOR-swizzled [e][d] ----------------
__global__ void tw_kernel(const float* __restrict__ w,
                          unsigned short* __restrict__ wth,
                          unsigned short* __restrict__ wtl) {
  __shared__ float t[64][65];
  int bx = blockIdx.x;
  int dt = bx >> 2, et = bx & 3;
  int d0 = dt * 64, e0 = et * 64;
  int tid = threadIdx.x;
  int rr = tid >> 4, c4 = (tid & 15) * 4;
#pragma unroll
  for (int k = 0; k < 4; ++k) {
    int row = rr + k * 16;   // d index
    float4 v = *(const float4*)(w + (size_t)(d0 + row) * DD + e0 + c4);
    t[row][c4 + 0] = v.x; t[row][c4 + 1] = v.y; t[row][c4 + 2] = v.z; t[row][c4 + 3] = v.w;
  }
  __syncthreads();
#pragma unroll
  for (int k = 0; k < 4; ++k) {
    int e = rr + k * 16;
    int eg = e0 + e;
    ushort4 h, l;
    float v0 = t[c4 + 0][e]; h.x = f2h(v0); l.x = f2h(v0 - h2f(h.x));
    float v1 = t[c4 + 1][e]; h.y = f2h(v1); l.y = f2h(v1 - h2f(h.y));
    float v2 = t[c4 + 2][e]; h.z = f2h(v2); l.z = f2h(v2 - h2f(h.z));
    float v3 = t[c4 + 3][e]; h.w = f2h(v3); l.w = f2h(v3 - h2f(h.w));
    int dd = d0 + c4;
    int u = dd >> 3, sub = dd & 7;
    size_t off = (size_t)eg * DD + ((u ^ (eg & 7)) * 8) + sub;
    *(ushort4*)(wth + off) = h;
    *(ushort4*)(wtl + off) = l;
  }
}

// ---------------- Q = x @ W  (2-term fp16 MFMA), writes qf fp16 row-major ----------------
__global__ __launch_bounds__(256, 2) void qgemm_kernel(
    const float* __restrict__ x, const unsigned short* __restrict__ wth,
    const unsigned short* __restrict__ wtl, unsigned short* __restrict__ qf) {
  __shared__ unsigned short wb[2][64 * 256];   // 64 KB
  const int tid = threadIdx.x;
  const int lane = tid & 63;
  const int wv = tid >> 6;
  const int quad = lane >> 4;
  const int l16 = lane & 15;
  const int m0 = blockIdx.x * 64;

  // x fragments (fp16 in regs)
  half8 xf[8];
  {
    const float* xr = x + (size_t)(m0 + wv * 16 + l16) * DD;
#pragma unroll
    for (int c = 0; c < 8; ++c) {
      float4 a = *(const float4*)(xr + c * 32 + quad * 8);
      float4 b = *(const float4*)(xr + c * 32 + quad * 8 + 4);
      half8 v;
      v[0] = (_Float16)a.x; v[1] = (_Float16)a.y; v[2] = (_Float16)a.z; v[3] = (_Float16)a.w;
      v[4] = (_Float16)b.x; v[5] = (_Float16)b.y; v[6] = (_Float16)b.z; v[7] = (_Float16)b.w;
      xf[c] = v;
    }
  }

#pragma unroll 1
  for (int eg = 0; eg < 4; ++eg) {
    // stage 64 e-rows of W^T hi+lo into LDS (linear copy; source pre-swizzled)
    uint4 t0[8], t1[8];
    {
      const unsigned short* sh = wth + (size_t)(eg * 64) * DD;
      const unsigned short* sl = wtl + (size_t)(eg * 64) * DD;
#pragma unroll
      for (int i = 0; i < 8; ++i) {
        t0[i] = *(const uint4*)(sh + tid * 64 + i * 8);
        t1[i] = *(const uint4*)(sl + tid * 64 + i * 8);
      }
    }
    __syncthreads();   // previous eg reads done
#pragma unroll
    for (int i = 0; i < 8; ++i) {
      *(uint4*)(wb[0] + tid * 64 + i * 8) = t0[i];
      *(uint4*)(wb[1] + tid * 64 + i * 8) = t1[i];
    }
    __syncthreads();
#pragma unroll
    for (int etl = 0; etl < 4; ++etl) {
      int rloc = etl * 16 + l16;
      f32x4 acc; acc[0] = acc[1] = acc[2] = acc[3] = 0.f;
#pragma unroll
      for (int c = 0; c < 8; ++c) {
        int off = rloc * DD + (((4 * c + quad) ^ (rloc & 7)) * 8);
        half8 wh = *(const half8*)(wb[0] + off);
        half8 wl = *(const half8*)(wb[1] + off);
        acc = __builtin_amdgcn_mfma_f32_16x16x32_f16(xf[c], wh, acc, 0, 0, 0);
        acc = __builtin_amdgcn_mfma_f32_16x16x32_f16(xf[c], wl, acc, 0, 0, 0);
      }
      int e = eg * 64 + etl * 16 + l16;
#pragma unroll
      for (int rg = 0; rg < 4; ++rg) {
        qf[(size_t)(m0 + wv * 16 + 4 * quad + rg) * DD + e] = f2h(acc[rg]);
      }
    }
  }
}

// ---------------- flash attention v3 (fp16) ----------------
// 4 waves = 2 q-groups x 2 roles; QBLK=64 (32q/wave), grid 512 -> 2 blocks/CU.
// fp16 single-MFMA QK^T; V preloaded to regs at top of kt (T14); K reg-prefetched,
// staged after b1; defer-max online softmax with cross-pair exchange.
__global__ __launch_bounds__(256, 2) void attn_kernel(
    const unsigned short* __restrict__ ksw, const unsigned short* __restrict__ vt,
    const unsigned short* __restrict__ qf, float* __restrict__ out) {
  __shared__ unsigned short kls[KVB * DD];     // 16 KB
  __shared__ unsigned short pls[2 * 32 * 32];  // 4 KB
  __shared__ float scm[2][2][32];
  __shared__ float scs[2][2][32];

  const int tid = threadIdx.x;
  const int lane = tid & 63;
  const int wv = tid >> 6;       // 0..3
  const int g = wv >> 1;         // q-group
  const int h = wv & 1;          // j-half (QK^T) / d-half (PV)
  const int quad = lane >> 4;
  const int l16 = lane & 15;

  int bx = blockIdx.x;
  int lbx = (bx & 7) * 64 + (bx >> 3);   // XCD-chunked (512 = 8*64)
  const int b = lbx >> 5;
  const int qbase = (lbx & 31) * 64 + g * 32;

  const size_t abase = (size_t)b * NA * DD;
  const size_t vbase = (size_t)b * (size_t)DD * NA;

  // Q fragments (fp16, from global)
  half8 qh[2][8];
#pragma unroll
  for (int qt = 0; qt < 2; ++qt) {
    const size_t qrow = ((size_t)b * NI + qbase + qt * 16 + l16) * DD;
#pragma unroll
    for (int c = 0; c < 8; ++c)
      qh[qt][c] = *(const half8*)(qf + qrow + c * 32 + quad * 8);
  }

  f32x4 acc[2][8];
#pragma unroll
  for (int qt = 0; qt < 2; ++qt)
#pragma unroll
    for (int dt = 0; dt < 8; ++dt) { acc[qt][dt][0] = 0.f; acc[qt][dt][1] = 0.f; acc[qt][dt][2] = 0.f; acc[qt][dt][3] = 0.f; }
  float m0r = -INFINITY, m1r = -INFINITY;
  float l0 = 0.f, l1 = 0.f;

  // prologue: stage K tile 0 (linear; source pre-swizzled)
  {
    const unsigned short* s = ksw + abase;
#pragma unroll
    for (int i = 0; i < 4; ++i)
      *(uint4*)(kls + tid * 32 + i * 8) = *(const uint4*)(s + tid * 32 + i * 8);
  }
  __syncthreads();

  const int jr = h * 16 + l16;
  const int key0 = (l16 ^ (l16 >> 2)) & 3;
  const int key1 = ((16 + l16) ^ ((16 + l16) >> 2)) & 3;

#pragma unroll 1
  for (int kt = 0; kt < NT; ++kt) {
    const int jb = kt * KVB;

    // ---- V preload (T14: consumed in PV, ~full kt of cover) ----
    half8 vpre[8];
#pragma unroll
    for (int dt = 0; dt < 8; ++dt) {
      int d = h * 128 + dt * 16 + l16;
      vpre[dt] = *(const half8*)(vt + vbase + (size_t)d * NA + jb + quad * 8);
    }
    // ---- K prefetch (regs) ----
    uint4 kpf[4];
    if (kt + 1 < NT) {
      const unsigned short* s = ksw + abase + (size_t)(jb + KVB) * DD;
#pragma unroll
      for (int i = 0; i < 4; ++i) kpf[i] = *(const uint4*)(s + tid * 32 + i * 8);
    }

    // ---- QK^T (fp16 single) ----
    f32x4 st0, st1;
    st0[0] = st0[1] = st0[2] = st0[3] = 0.f;
    st1[0] = st1[1] = st1[2] = st1[3] = 0.f;
    __builtin_amdgcn_s_setprio(1);
#pragma unroll
    for (int c = 0; c < 8; ++c) {
      half8 kfr = *(const half8*)(kls + jr * DD + (((4 * c + quad) ^ (jr & 7)) * 8));
      st0 = __builtin_amdgcn_mfma_f32_16x16x32_f16(kfr, qh[0][c], st0, 0, 0, 0);
      st1 = __builtin_amdgcn_mfma_f32_16x16x32_f16(kfr, qh[1][c], st1, 0, 0, 0);
    }
    __builtin_amdgcn_s_setprio(0);

    // ---- partial max over own 16 j ----
    float p0 = fmaxf(fmaxf(st0[0], st0[1]), fmaxf(st0[2], st0[3]));
    float p1 = fmaxf(fmaxf(st1[0], st1[1]), fmaxf(st1[2], st1[3]));
    p0 = fmaxf(p0, __shfl_xor(p0, 16)); p0 = fmaxf(p0, __shfl_xor(p0, 32));
    p1 = fmaxf(p1, __shfl_xor(p1, 16)); p1 = fmaxf(p1, __shfl_xor(p1, 32));
    if (quad == 0) { scm[g][h][l16] = p0; scm[g][h][16 + l16] = p1; }
    __syncthreads();   // b1: scm exchange + all K reads done

    float pm0 = fmaxf(p0, scm[g][h ^ 1][l16]);
    float pm1 = fmaxf(p1, scm[g][h ^ 1][16 + l16]);
    bool upd = __any((pm0 > m0r + 8.f) || (pm1 > m1r + 8.f)) != 0;
    if (upd) {
      float mn0 = fmaxf(m0r, pm0), mn1 = fmaxf(m1r, pm1);
      float sc0 = __expf(m0r - mn0), sc1 = __expf(m1r - mn1);
      l0 *= sc0; l1 *= sc1;
      float a0 = __shfl(sc0, 4 * quad + 0), a1 = __shfl(sc0, 4 * quad + 1);
      float a2 = __shfl(sc0, 4 * quad + 2), a3 = __shfl(sc0, 4 * quad + 3);
      float b0 = __shfl(sc1, 4 * quad + 0), b1 = __shfl(sc1, 4 * quad + 1);
      float b2 = __shfl(sc1, 4 * quad + 2), b3 = __shfl(sc1, 4 * quad + 3);
#pragma unroll
      for (int dt = 0; dt < 8; ++dt) {
        acc[0][dt][0] *= a0; acc[0][dt][1] *= a1; acc[0][dt][2] *= a2; acc[0][dt][3] *= a3;
        acc[1][dt][0] *= b0; acc[1][dt][1] *= b1; acc[1][dt][2] *= b2; acc[1][dt][3] *= b3;
      }
      m0r = mn0; m1r = mn1;
    }

    // ---- stage next K (buffer free after b1; visible after b2) ----
    if (kt + 1 < NT) {
#pragma unroll
      for (int i = 0; i < 4; ++i) *(uint4*)(kls + tid * 32 + i * 8) = kpf[i];
    }

    // ---- exp, partial sums, P write (fp16) ----
    float e00 = __expf(st0[0] - m0r), e01 = __expf(st0[1] - m0r);
    float e02 = __expf(st0[2] - m0r), e03 = __expf(st0[3] - m0r);
    float e10 = __expf(st1[0] - m1r), e11 = __expf(st1[1] - m1r);
    float e12 = __expf(st1[2] - m1r), e13 = __expf(st1[3] - m1r);
    float s0 = (e00 + e01) + (e02 + e03);
    float s1 = (e10 + e11) + (e12 + e13);
    s0 += __shfl_xor(s0, 16); s0 += __shfl_xor(s0, 32);
    s1 += __shfl_xor(s1, 16); s1 += __shfl_xor(s1, 32);
    {
      int uw = h * 2 + (quad >> 1);
      int sub = (quad & 1) * 4;
      ushort4 pk;
      pk.x = f2h(e00); pk.y = f2h(e01); pk.z = f2h(e02); pk.w = f2h(e03);
      *(ushort4*)(pls + g * 1024 + l16 * 32 + ((uw ^ key0) * 8) + sub) = pk;
      pk.x = f2h(e10); pk.y = f2h(e11); pk.z = f2h(e12); pk.w = f2h(e13);
      *(ushort4*)(pls + g * 1024 + (16 + l16) * 32 + ((uw ^ key1) * 8) + sub) = pk;
    }
    if (quad == 0) { scs[g][h][l16] = s0; scs[g][h][16 + l16] = s1; }
    __syncthreads();   // b2: P + scs + new K visible

    l0 += s0 + scs[g][h ^ 1][l16];
    l1 += s1 + scs[g][h ^ 1][16 + l16];

    // ---- PV (own d-half), V from regs ----
    half8 pa0 = *(const half8*)(pls + g * 1024 + l16 * 32 + ((quad ^ key0) * 8));
    half8 pa1 = *(const half8*)(pls + g * 1024 + (16 + l16) * 32 + ((quad ^ key1) * 8));
    __builtin_amdgcn_s_setprio(1);
#pragma unroll
    for (int dt = 0; dt < 8; ++dt) {
      acc[0][dt] = __builtin_amdgcn_mfma_f32_16x16x32_f16(pa0, vpre[dt], acc[0][dt], 0, 0, 0);
      acc[1][dt] = __builtin_amdgcn_mfma_f32_16x16x32_f16(pa1, vpre[dt], acc[1][dt], 0, 0, 0);
    }
    __builtin_amdgcn_s_setprio(0);
  }

  // ---- epilogue ----
  float inv0 = 1.0f / l0, inv1 = 1.0f / l1;
  float i00 = __shfl(inv0, 4 * quad + 0), i01 = __shfl(inv0, 4 * quad + 1);
  float i02 = __shfl(inv0, 4 * quad + 2), i03 = __shfl(inv0, 4 * quad + 3);
  float i10 = __shfl(inv1, 4 * quad + 0), i11 = __shfl(inv1, 4 * quad + 1);
  float i12 = __shfl(inv1, 4 * quad + 2), i13 = __shfl(inv1, 4 * quad + 3);
  size_t ob = ((size_t)b * NI + qbase) * DD + h * 128;
#pragma unroll
  for (int dt = 0; dt < 8; ++dt) {
    int d = dt * 16 + l16;
    out[ob + (size_t)(4 * quad + 0) * DD + d] = acc[0][dt][0] * i00;
    out[ob + (size_t)(4 * quad + 1) * DD + d] = acc[0][dt][1] * i01;
    out[ob + (size_t)(4 * quad + 2) * DD + d] = acc[0][dt][2] * i02;
    out[ob + (size_t)(4 * quad + 3) * DD + d] = acc[0][dt][3] * i03;
    out[ob + (size_t)(16 + 4 * quad + 0) * DD + d] = acc[1][dt][0] * i10;
    out[ob + (size_t)(16 + 4 * quad + 1) * DD + d] = acc[1][dt][1] * i11;
    out[ob + (size_t)(16 + 4 * quad + 2) * DD + d] = acc[1][dt][2] * i12;
    out[ob + (size_t)(16 + 4 * quad + 3) * DD + d] = acc[1][dt][3] * i13;
  }
}

extern "C" void kernel_launch(void* const* d_in, const int* in_sizes, int n_in,
                              void* d_out, int out_size, void* d_ws, size_t ws_size,
                              hipStream_t stream) {
  const float* x = (const float*)d_in[0];        // [16,2048,256]
  const float* att = (const float*)d_in[1];      // [16,2048,256]
  const float* W = (const float*)d_in[2];        // [256,256]
  float* out = (float*)d_out;

  const size_t NE = (size_t)BB * NA * DD;        // 8388608
  unsigned short* w0  = (unsigned short*)d_ws;
  unsigned short* ksw = w0;
  unsigned short* vt  = w0 + NE;
  unsigned short* qf  = w0 + 2 * NE;
  unsigned short* wth = w0 + 3 * NE;
  unsigned short* wtl = w0 + 3 * NE + (size_t)DD * DD;

  prep_kernel<<<2048, 256, 0, stream>>>(att, ksw, vt);
  tw_kernel<<<16, 256, 0, stream>>>(W, wth, wtl);
  qgemm_kernel<<<512, 256, 0, stream>>>(x, wth, wtl, qf);
  attn_kernel<<<512, 256, 0, stream>>>(ksw, vt, qf, out);
}

// Round 4
// 212.567 us; speedup vs baseline: 1.6914x; 1.6057x over previous
//
#include <hip/hip_runtime.h>
#include <hip/hip_bf16.h>

#define BB 16
#define NI 2048
#define NA 2048
#define DD 256
#define KVB 32
#define NT (NA / KVB)   // 64

typedef _Float16 half8 __attribute__((ext_vector_type(8)));
typedef __attribute__((ext_vector_type(4))) float f32x4;

static __device__ __forceinline__ unsigned short f2h(float f) {
  union { _Float16 h; unsigned short u; } x; x.h = (_Float16)f; return x.u;
}
static __device__ __forceinline__ float h2f(unsigned short u) {
  union { _Float16 h; unsigned short u; } x; x.u = u; return (float)x.h;
}

// ---------------- prep: attendee -> ksw (fp16, row-XOR-swizzled) + vt (fp16, transposed) ----
__global__ void prep_kernel(const float* __restrict__ a,
                            unsigned short* __restrict__ ksw,
                            unsigned short* __restrict__ vt) {
  __shared__ float t[64][65];
  int bx = blockIdx.x;
  int b = bx >> 7;
  int r = bx & 127;
  int jt = r >> 2, dt = r & 3;
  int j0 = jt * 64, d0 = dt * 64;
  int tid = threadIdx.x;
  int rr = tid >> 4, c4 = tid & 15;
#pragma unroll
  for (int k = 0; k < 4; ++k) {
    int row = rr + k * 16;
    int j = j0 + row;
    float4 v = *(const float4*)(a + ((size_t)b * NA + j) * DD + d0 + c4 * 4);
    ushort4 hh;
    hh.x = f2h(v.x); hh.y = f2h(v.y); hh.z = f2h(v.z); hh.w = f2h(v.w);
    int dd = d0 + c4 * 4;
    int u = dd >> 3, sub = dd & 7;            // sub in {0,4}
    int us = u ^ (j & 7);
    *(ushort4*)(ksw + ((size_t)b * NA + j) * DD + us * 8 + sub) = hh;
    t[row][c4 * 4 + 0] = v.x; t[row][c4 * 4 + 1] = v.y;
    t[row][c4 * 4 + 2] = v.z; t[row][c4 * 4 + 3] = v.w;
  }
  __syncthreads();
#pragma unroll
  for (int k = 0; k < 4; ++k) {
    int d = rr + k * 16;
    ushort4 o;
    o.x = f2h(t[c4 * 4 + 0][d]); o.y = f2h(t[c4 * 4 + 1][d]);
    o.z = f2h(t[c4 * 4 + 2][d]); o.w = f2h(t[c4 * 4 + 3][d]);
    *(ushort4*)(vt + ((size_t)b * DD + d0 + d) * NA + j0 + c4 * 4) = o;
  }
}

// ---------------- tw: W -> W^T hi/lo fp16, row-XOR-swizzled [e][d] ----------------
__global__ void tw_kernel(const float* __restrict__ w,
                          unsigned short* __restrict__ wth,
                          unsigned short* __restrict__ wtl) {
  __shared__ float t[64][65];
  int bx = blockIdx.x;
  int dt = bx >> 2, et = bx & 3;
  int d0 = dt * 64, e0 = et * 64;
  int tid = threadIdx.x;
  int rr = tid >> 4, c4 = (tid & 15) * 4;
#pragma unroll
  for (int k = 0; k < 4; ++k) {
    int row = rr + k * 16;   // d index
    float4 v = *(const float4*)(w + (size_t)(d0 + row) * DD + e0 + c4);
    t[row][c4 + 0] = v.x; t[row][c4 + 1] = v.y; t[row][c4 + 2] = v.z; t[row][c4 + 3] = v.w;
  }
  __syncthreads();
#pragma unroll
  for (int k = 0; k < 4; ++k) {
    int e = rr + k * 16;
    int eg = e0 + e;
    ushort4 h, l;
    float v0 = t[c4 + 0][e]; h.x = f2h(v0); l.x = f2h(v0 - h2f(h.x));
    float v1 = t[c4 + 1][e]; h.y = f2h(v1); l.y = f2h(v1 - h2f(h.y));
    float v2 = t[c4 + 2][e]; h.z = f2h(v2); l.z = f2h(v2 - h2f(h.z));
    float v3 = t[c4 + 3][e]; h.w = f2h(v3); l.w = f2h(v3 - h2f(h.w));
    int dd = d0 + c4;
    int u = dd >> 3, sub = dd & 7;
    size_t off = (size_t)eg * DD + ((u ^ (eg & 7)) * 8) + sub;
    *(ushort4*)(wth + off) = h;
    *(ushort4*)(wtl + off) = l;
  }
}

// ---------------- Q = x @ W  (2-term fp16 MFMA), writes qf fp16 row-major ----------------
__global__ __launch_bounds__(256, 2) void qgemm_kernel(
    const float* __restrict__ x, const unsigned short* __restrict__ wth,
    const unsigned short* __restrict__ wtl, unsigned short* __restrict__ qf) {
  __shared__ unsigned short wb[2][64 * 256];   // 64 KB
  const int tid = threadIdx.x;
  const int lane = tid & 63;
  const int wv = tid >> 6;
  const int quad = lane >> 4;
  const int l16 = lane & 15;
  const int m0 = blockIdx.x * 64;

  half8 xf[8];
  {
    const float* xr = x + (size_t)(m0 + wv * 16 + l16) * DD;
#pragma unroll
    for (int c = 0; c < 8; ++c) {
      float4 a = *(const float4*)(xr + c * 32 + quad * 8);
      float4 b = *(const float4*)(xr + c * 32 + quad * 8 + 4);
      half8 v;
      v[0] = (_Float16)a.x; v[1] = (_Float16)a.y; v[2] = (_Float16)a.z; v[3] = (_Float16)a.w;
      v[4] = (_Float16)b.x; v[5] = (_Float16)b.y; v[6] = (_Float16)b.z; v[7] = (_Float16)b.w;
      xf[c] = v;
    }
  }

#pragma unroll 1
  for (int eg = 0; eg < 4; ++eg) {
    uint4 t0[8], t1[8];
    {
      const unsigned short* sh = wth + (size_t)(eg * 64) * DD;
      const unsigned short* sl = wtl + (size_t)(eg * 64) * DD;
#pragma unroll
      for (int i = 0; i < 8; ++i) {
        t0[i] = *(const uint4*)(sh + (i * 256 + tid) * 8);
        t1[i] = *(const uint4*)(sl + (i * 256 + tid) * 8);
      }
    }
    __syncthreads();
#pragma unroll
    for (int i = 0; i < 8; ++i) {
      *(uint4*)(wb[0] + (i * 256 + tid) * 8) = t0[i];
      *(uint4*)(wb[1] + (i * 256 + tid) * 8) = t1[i];
    }
    __syncthreads();
#pragma unroll
    for (int etl = 0; etl < 4; ++etl) {
      int rloc = etl * 16 + l16;
      f32x4 acc; acc[0] = acc[1] = acc[2] = acc[3] = 0.f;
#pragma unroll
      for (int c = 0; c < 8; ++c) {
        int off = rloc * DD + (((4 * c + quad) ^ (rloc & 7)) * 8);
        half8 wh = *(const half8*)(wb[0] + off);
        half8 wl = *(const half8*)(wb[1] + off);
        acc = __builtin_amdgcn_mfma_f32_16x16x32_f16(xf[c], wh, acc, 0, 0, 0);
        acc = __builtin_amdgcn_mfma_f32_16x16x32_f16(xf[c], wl, acc, 0, 0, 0);
      }
      int e = eg * 64 + etl * 16 + l16;
#pragma unroll
      for (int rg = 0; rg < 4; ++rg) {
        qf[(size_t)(m0 + wv * 16 + 4 * quad + rg) * DD + e] = f2h(acc[rg]);
      }
    }
  }
}

// ---------------- flash attention v4: independent waves, 1 barrier/kt ----------------
// 4 waves = 2 pairs; each pair owns 32 q. BOTH waves of a pair compute QK^T for the
// full 32 q (duplicated, barrier-free); PV splits d (128 each). Softmax fully
// per-wave in-register. P via wave-private LDS (no barrier). K double-buffered:
// reg-prefetch at top, ds_write at end of body (full-body latency cover).
__global__ __launch_bounds__(256, 2) void attn_kernel(
    const unsigned short* __restrict__ ksw, const unsigned short* __restrict__ vt,
    const unsigned short* __restrict__ qf, float* __restrict__ out) {
  __shared__ unsigned short kls[2][KVB * DD];   // 32 KB
  __shared__ unsigned short pls[4][32 * 40];    // 10 KB (pad 40 keeps 16B align, ~2-way banks)

  const int tid = threadIdx.x;
  const int lane = tid & 63;
  const int wv = tid >> 6;       // 0..3
  const int p = wv >> 1;         // pair
  const int h = wv & 1;          // d-half
  const int quad = lane >> 4;
  const int l16 = lane & 15;

  int bx = blockIdx.x;
  int lbx = (bx & 7) * 64 + (bx >> 3);   // XCD-chunked (512 = 8*64)
  const int b = lbx >> 5;
  const int qbase = (lbx & 31) * 64 + p * 32;

  const size_t abase = (size_t)b * NA * DD;
  const size_t vbase = (size_t)b * (size_t)DD * NA;

  // Q fragments (both q-tiles of the pair)
  half8 qh[2][8];
#pragma unroll
  for (int qt = 0; qt < 2; ++qt) {
    const size_t qrow = ((size_t)b * NI + qbase + qt * 16 + l16) * DD;
#pragma unroll
    for (int c = 0; c < 8; ++c)
      qh[qt][c] = *(const half8*)(qf + qrow + c * 32 + quad * 8);
  }

  f32x4 acc[2][8];
#pragma unroll
  for (int qt = 0; qt < 2; ++qt)
#pragma unroll
    for (int dt = 0; dt < 8; ++dt) { acc[qt][dt][0] = 0.f; acc[qt][dt][1] = 0.f; acc[qt][dt][2] = 0.f; acc[qt][dt][3] = 0.f; }
  float m0r = -INFINITY, m1r = -INFINITY;
  float l0 = 0.f, l1 = 0.f;

  // prologue: stage K tile 0 (16B-interleaved, conflict-free)
  {
    const unsigned short* s = ksw + abase;
#pragma unroll
    for (int i = 0; i < 4; ++i)
      *(uint4*)(kls[0] + (i * 256 + tid) * 8) = *(const uint4*)(s + (i * 256 + tid) * 8);
  }
  __syncthreads();

  unsigned short* pw = pls[wv];

#pragma unroll 1
  for (int kt = 0; kt < NT; ++kt) {
    const int jb = kt * KVB;

    // ---- V B-frags (own d-half) from L2, consumed at end of body ----
    half8 vb[8];
#pragma unroll
    for (int dt = 0; dt < 8; ++dt)
      vb[dt] = *(const half8*)(vt + vbase + (size_t)(h * 128 + dt * 16 + l16) * NA + jb + quad * 8);

    // ---- K(kt+1) prefetch into regs ----
    uint4 kf0, kf1, kf2, kf3;
    if (kt + 1 < NT) {
      const unsigned short* s = ksw + abase + (size_t)(jb + KVB) * DD;
      kf0 = *(const uint4*)(s + (0 * 256 + tid) * 8);
      kf1 = *(const uint4*)(s + (1 * 256 + tid) * 8);
      kf2 = *(const uint4*)(s + (2 * 256 + tid) * 8);
      kf3 = *(const uint4*)(s + (3 * 256 + tid) * 8);
    }

    // ---- QK^T: S^T[j, q] for full 32 j x 32 q ----
    const unsigned short* kb = kls[kt & 1];
    f32x4 st[2][2];
#pragma unroll
    for (int a = 0; a < 2; ++a)
#pragma unroll
      for (int c = 0; c < 2; ++c) { st[a][c][0] = 0.f; st[a][c][1] = 0.f; st[a][c][2] = 0.f; st[a][c][3] = 0.f; }
#pragma unroll
    for (int c = 0; c < 8; ++c) {
#pragma unroll
      for (int jt = 0; jt < 2; ++jt) {
        int jr = jt * 16 + l16;
        half8 kfr = *(const half8*)(kb + jr * DD + (((4 * c + quad) ^ (jr & 7)) * 8));
        st[0][jt] = __builtin_amdgcn_mfma_f32_16x16x32_f16(kfr, qh[0][c], st[0][jt], 0, 0, 0);
        st[1][jt] = __builtin_amdgcn_mfma_f32_16x16x32_f16(kfr, qh[1][c], st[1][jt], 0, 0, 0);
      }
    }

    // ---- per-wave softmax (lane owns full row q=l16 across regs+quads) ----
    float mt0 = fmaxf(fmaxf(fmaxf(st[0][0][0], st[0][0][1]), fmaxf(st[0][0][2], st[0][0][3])),
                      fmaxf(fmaxf(st[0][1][0], st[0][1][1]), fmaxf(st[0][1][2], st[0][1][3])));
    float mt1 = fmaxf(fmaxf(fmaxf(st[1][0][0], st[1][0][1]), fmaxf(st[1][0][2], st[1][0][3])),
                      fmaxf(fmaxf(st[1][1][0], st[1][1][1]), fmaxf(st[1][1][2], st[1][1][3])));
    mt0 = fmaxf(mt0, __shfl_xor(mt0, 16)); mt0 = fmaxf(mt0, __shfl_xor(mt0, 32));
    mt1 = fmaxf(mt1, __shfl_xor(mt1, 16)); mt1 = fmaxf(mt1, __shfl_xor(mt1, 32));
    bool upd = __any((mt0 > m0r + 8.f) || (mt1 > m1r + 8.f)) != 0;
    if (upd) {
      float mn0 = fmaxf(m0r, mt0), mn1 = fmaxf(m1r, mt1);
      float sc0 = __expf(m0r - mn0), sc1 = __expf(m1r - mn1);
      l0 *= sc0; l1 *= sc1;
#pragma unroll
      for (int rg = 0; rg < 4; ++rg) {
        float a0 = __shfl(sc0, 4 * quad + rg);
        float a1 = __shfl(sc1, 4 * quad + rg);
#pragma unroll
        for (int dt = 0; dt < 8; ++dt) { acc[0][dt][rg] *= a0; acc[1][dt][rg] *= a1; }
      }
      m0r = mn0; m1r = mn1;
    }

    // ---- exp + row sums + P write (wave-private LDS, no barrier) ----
    float e0[2][4], e1[2][4];
#pragma unroll
    for (int jt = 0; jt < 2; ++jt)
#pragma unroll
      for (int rg = 0; rg < 4; ++rg) {
        e0[jt][rg] = __expf(st[0][jt][rg] - m0r);
        e1[jt][rg] = __expf(st[1][jt][rg] - m1r);
      }
    float s0 = (e0[0][0] + e0[0][1]) + (e0[0][2] + e0[0][3]) +
               (e0[1][0] + e0[1][1]) + (e0[1][2] + e0[1][3]);
    float s1 = (e1[0][0] + e1[0][1]) + (e1[0][2] + e1[0][3]) +
               (e1[1][0] + e1[1][1]) + (e1[1][2] + e1[1][3]);
    s0 += __shfl_xor(s0, 16); s0 += __shfl_xor(s0, 32);
    s1 += __shfl_xor(s1, 16); s1 += __shfl_xor(s1, 32);
    l0 += s0; l1 += s1;
#pragma unroll
    for (int jt = 0; jt < 2; ++jt) {
      ushort4 pk;
      pk.x = f2h(e0[jt][0]); pk.y = f2h(e0[jt][1]); pk.z = f2h(e0[jt][2]); pk.w = f2h(e0[jt][3]);
      *(ushort4*)(pw + (0 * 16 + l16) * 40 + jt * 16 + quad * 4) = pk;
      pk.x = f2h(e1[jt][0]); pk.y = f2h(e1[jt][1]); pk.z = f2h(e1[jt][2]); pk.w = f2h(e1[jt][3]);
      *(ushort4*)(pw + (1 * 16 + l16) * 40 + jt * 16 + quad * 4) = pk;
    }
    half8 pa0 = *(const half8*)(pw + (0 * 16 + l16) * 40 + quad * 8);
    half8 pa1 = *(const half8*)(pw + (1 * 16 + l16) * 40 + quad * 8);

    // ---- PV (own d-half), V from regs ----
#pragma unroll
    for (int dt = 0; dt < 8; ++dt) {
      acc[0][dt] = __builtin_amdgcn_mfma_f32_16x16x32_f16(pa0, vb[dt], acc[0][dt], 0, 0, 0);
      acc[1][dt] = __builtin_amdgcn_mfma_f32_16x16x32_f16(pa1, vb[dt], acc[1][dt], 0, 0, 0);
    }

    // ---- stage next K into other buffer (end of body: full cover) ----
    if (kt + 1 < NT) {
      unsigned short* d = kls[(kt + 1) & 1];
      *(uint4*)(d + (0 * 256 + tid) * 8) = kf0;
      *(uint4*)(d + (1 * 256 + tid) * 8) = kf1;
      *(uint4*)(d + (2 * 256 + tid) * 8) = kf2;
      *(uint4*)(d + (3 * 256 + tid) * 8) = kf3;
    }
    __syncthreads();
  }

  // ---- epilogue ----
  float inv0 = 1.0f / l0, inv1 = 1.0f / l1;
  size_t ob = ((size_t)b * NI + qbase) * DD + h * 128;
#pragma unroll
  for (int rg = 0; rg < 4; ++rg) {
    float i0 = __shfl(inv0, 4 * quad + rg);
    float i1 = __shfl(inv1, 4 * quad + rg);
#pragma unroll
    for (int dt = 0; dt < 8; ++dt) {
      int d = dt * 16 + l16;
      out[ob + (size_t)(4 * quad + rg) * DD + d] = acc[0][dt][rg] * i0;
      out[ob + (size_t)(16 + 4 * quad + rg) * DD + d] = acc[1][dt][rg] * i1;
    }
  }
}

extern "C" void kernel_launch(void* const* d_in, const int* in_sizes, int n_in,
                              void* d_out, int out_size, void* d_ws, size_t ws_size,
                              hipStream_t stream) {
  const float* x = (const float*)d_in[0];        // [16,2048,256]
  const float* att = (const float*)d_in[1];      // [16,2048,256]
  const float* W = (const float*)d_in[2];        // [256,256]
  float* out = (float*)d_out;

  const size_t NE = (size_t)BB * NA * DD;        // 8388608
  unsigned short* w0  = (unsigned short*)d_ws;
  unsigned short* ksw = w0;
  unsigned short* vt  = w0 + NE;
  unsigned short* qf  = w0 + 2 * NE;
  unsigned short* wth = w0 + 3 * NE;
  unsigned short* wtl = w0 + 3 * NE + (size_t)DD * DD;

  prep_kernel<<<2048, 256, 0, stream>>>(att, ksw, vt);
  tw_kernel<<<16, 256, 0, stream>>>(W, wth, wtl);
  qgemm_kernel<<<512, 256, 0, stream>>>(x, wth, wtl, qf);
  attn_kernel<<<512, 256, 0, stream>>>(ksw, vt, qf, out);
}